// Round 2
// 723.482 us; speedup vs baseline: 1.1196x; 1.1196x over previous
//
#include <hip/hip_runtime.h>
#include <cstddef>
#include <cstdint>

// Problem constants
static constexpr int B_  = 8;
static constexpr int CIN = 16;
static constexpr int F_  = 1024;
static constexpr int T_  = 512;
static constexpr int D_  = 1024;
static constexpr int L_  = 4;
static constexpr int NT  = 512;         // N_TOKENS
static constexpr int M_  = T_ * B_;     // 4096 GEMM rows (m = t*8 + b)
static constexpr int K3  = 3 * D_;      // 3072
static constexpr int NP  = 4 * D_;      // 4096 = padded gate-interleaved N

typedef __attribute__((ext_vector_type(8))) short short8;   // 8 bf16 in 4 VGPRs
typedef __attribute__((ext_vector_type(4))) float floatx4;  // MFMA accumulator

__device__ __forceinline__ unsigned short f2bf(float f) {
    unsigned int u = __builtin_bit_cast(unsigned int, f);
    u += 0x7FFFu + ((u >> 16) & 1u);    // round-to-nearest-even
    return (unsigned short)(u >> 16);
}
__device__ __forceinline__ float bf2f(unsigned short s) {
    unsigned int u = ((unsigned int)s) << 16;
    return __builtin_bit_cast(float, u);
}

// async 16B/lane global->LDS (lds base wave-uniform; HW scatters lane*16)
#define GLD16(g, l)                                                              \
    __builtin_amdgcn_global_load_lds(                                            \
        (__attribute__((address_space(1))) unsigned int*)(g),                    \
        (__attribute__((address_space(3))) unsigned int*)(l), 16, 0, 0)

// ---------------------------------------------------------------------------
// Kernel 1: x_bf16[t][b][f] = relu( sum_c feats[b][c][f][t]*w[c] + bias )
// 32(f) x 64(t) tile, float4 reads along t, LDS transpose, ushort4 writes.
// ---------------------------------------------------------------------------
__global__ __launch_bounds__(256) void conv_relu_tr(
    const float* __restrict__ feats, const float* __restrict__ wv,
    const float* __restrict__ bv, unsigned short* __restrict__ x0) {
    __shared__ float tile[32][68];      // [f][t], padded for float4 rows
    const int b  = blockIdx.z;
    const int f0 = blockIdx.y * 32;
    const int t0 = blockIdx.x * 64;
    const float bias = bv[0];

    const int t4 = threadIdx.x & 15;    // t-offset/4
    const int fi = threadIdx.x >> 4;    // 0..15
    #pragma unroll
    for (int fo = 0; fo < 32; fo += 16) {
        const int f = fo + fi;
        float4 acc = {bias, bias, bias, bias};
        const float* p = feats + (((size_t)b * CIN) * F_ + (f0 + f)) * T_ + t0 + t4 * 4;
        #pragma unroll
        for (int c = 0; c < CIN; ++c) {
            const float4 vv = *(const float4*)(p + (size_t)c * F_ * T_);
            const float w = wv[c];
            acc.x += w * vv.x; acc.y += w * vv.y;
            acc.z += w * vv.z; acc.w += w * vv.w;
        }
        acc.x = fmaxf(acc.x, 0.f); acc.y = fmaxf(acc.y, 0.f);
        acc.z = fmaxf(acc.z, 0.f); acc.w = fmaxf(acc.w, 0.f);
        *(float4*)&tile[f][t4 * 4] = acc;
    }
    __syncthreads();
    const int f4 = threadIdx.x & 7;     // f-offset/4
    const int tr = threadIdx.x >> 3;    // 0..31
    #pragma unroll
    for (int to = 0; to < 64; to += 32) {
        const int t = to + tr;
        unsigned short pk[4];
        #pragma unroll
        for (int q = 0; q < 4; ++q) pk[q] = f2bf(tile[f4 * 4 + q][t]);
        *(uint2*)&x0[(size_t)(t0 + t) * (B_ * D_) + (size_t)b * D_ + f0 + f4 * 4] =
            *(const uint2*)pk;
    }
}

// ---------------------------------------------------------------------------
// Kernel 2: weight prep (one launch, grid z = 0..16):
//  z<16: l=z>>2, j=z&3:  Wt[l][d*4+j][k] = bf16(sru_W[l][k][j*1024+d])
//        j==3 -> IDENTITY row e_d (routes x through the GEMM exactly)
//  z==16 (blockIdx.x<16): WtF[n][k] = bf16(fc_w[k][n])
// ---------------------------------------------------------------------------
__global__ __launch_bounds__(256) void prep_weights(
    const float* __restrict__ sru_W, const float* __restrict__ fc_w,
    unsigned short* __restrict__ Wt, unsigned short* __restrict__ WtF) {
    __shared__ float tile[32][33];
    const int z  = blockIdx.z;
    const int x  = threadIdx.x & 31;
    const int y8 = threadIdx.x >> 5;    // 0..7
    if (z < 16) {
        const int l = z >> 2, j = z & 3;
        const int d0 = blockIdx.x * 32;
        const int k0 = blockIdx.y * 32;
        unsigned short* Wo = Wt + (size_t)l * ((size_t)NP * D_);
        if (j < 3) {
            const float* W = sru_W + (size_t)l * D_ * K3;
            #pragma unroll
            for (int yo = 0; yo < 32; yo += 8)
                tile[yo + y8][x] = W[(size_t)(k0 + yo + y8) * K3 + j * D_ + d0 + x];
            __syncthreads();
            #pragma unroll
            for (int yo = 0; yo < 32; yo += 8) {
                const int dy = yo + y8;
                Wo[(size_t)((d0 + dy) * 4 + j) * D_ + k0 + x] = f2bf(tile[x][dy]);
            }
        } else {
            #pragma unroll
            for (int yo = 0; yo < 32; yo += 8) {
                const int dy = d0 + yo + y8;
                Wo[(size_t)(dy * 4 + 3) * D_ + k0 + x] =
                    (k0 + x == dy) ? (unsigned short)0x3F80u : (unsigned short)0u;
            }
        }
    } else {
        if (blockIdx.x >= NT / 32) return;
        const int n0 = blockIdx.x * 32;
        const int k0 = blockIdx.y * 32;
        #pragma unroll
        for (int yo = 0; yo < 32; yo += 8)
            tile[yo + y8][x] = fc_w[(size_t)(k0 + yo + y8) * NT + n0 + x];
        __syncthreads();
        #pragma unroll
        for (int yo = 0; yo < 32; yo += 8)
            WtF[(size_t)(n0 + yo + y8) * D_ + k0 + x] = f2bf(tile[x][yo + y8]);
    }
}

// ---------------------------------------------------------------------------
// Kernel 3: bf16 MFMA GEMM  C[M][N] = A[M][K] * Bt[N][K]^T  (m97 structure)
// kept for the FC GEMM only (MODE 1: fp32 out, +bias, row remap).
// ---------------------------------------------------------------------------
template <int MODE>
__global__ __launch_bounds__(256) void gemm_mfma(
    const unsigned short* __restrict__ A,   // [M][K] bf16
    const unsigned short* __restrict__ Bt,  // [N][K] bf16
    void* __restrict__ Cv, const float* __restrict__ bias,
    int N, int K) {
    __shared__ unsigned short As[128 * 32];
    __shared__ unsigned short Bs[128 * 32];

    const int tid  = threadIdx.x;
    const int lane = tid & 63;
    const int wid  = tid >> 6;
    const int m0 = blockIdx.y * 128;
    const int n0 = blockIdx.x * 128;
    const int wm = (wid >> 1) * 64;
    const int wn = (wid & 1) * 64;

    floatx4 acc[4][4];
    #pragma unroll
    for (int mi = 0; mi < 4; ++mi)
        #pragma unroll
        for (int ni = 0; ni < 4; ++ni)
            acc[mi][ni] = (floatx4){0.f, 0.f, 0.f, 0.f};

    const char* gA = (const char*)A;
    const char* gB = (const char*)Bt;
    const size_t rowstride = (size_t)K * 2;
    const size_t rA0 = (size_t)(m0 + (tid >> 2)) * rowstride + (tid & 3) * 16;
    const size_t rB0 = (size_t)(n0 + (tid >> 2)) * rowstride + (tid & 3) * 16;
    const size_t pstep = 64 * rowstride;
    char* sA = (char*)As;
    char* sB = (char*)Bs;
    const int ldsbase = wid * 1024;

    const int rsel = lane & 15;
    const int koff = (lane >> 4) * 16;   // byte offset of 8-bf16 k-group

    for (int k0 = 0; k0 < K; k0 += 32) {
        const size_t kb = (size_t)k0 * 2;
        GLD16(gA + rA0 + kb,         sA + ldsbase);
        GLD16(gA + rA0 + kb + pstep, sA + ldsbase + 4096);
        GLD16(gB + rB0 + kb,         sB + ldsbase);
        GLD16(gB + rB0 + kb + pstep, sB + ldsbase + 4096);
        __syncthreads();

        short8 af[4], bfv[4];
        #pragma unroll
        for (int mi = 0; mi < 4; ++mi)
            af[mi] = *(const short8*)(sA + ((wm + mi * 16 + rsel) * 64 + koff));
        #pragma unroll
        for (int ni = 0; ni < 4; ++ni)
            bfv[ni] = *(const short8*)(sB + ((wn + ni * 16 + rsel) * 64 + koff));
        #pragma unroll
        for (int mi = 0; mi < 4; ++mi)
            #pragma unroll
            for (int ni = 0; ni < 4; ++ni)
                acc[mi][ni] = __builtin_amdgcn_mfma_f32_16x16x32_bf16(
                    af[mi], bfv[ni], acc[mi][ni], 0, 0, 0);
        __syncthreads();
    }

    // C/D layout: col=lane&15, row=(lane>>4)*4+i  (verified m89/m91)
    const int cl = lane & 15;
    const int qr = lane >> 4;
    #pragma unroll
    for (int mi = 0; mi < 4; ++mi) {
        #pragma unroll
        for (int ni = 0; ni < 4; ++ni) {
            const int gn = n0 + wn + ni * 16 + cl;
            #pragma unroll
            for (int i = 0; i < 4; ++i) {
                const int gm = m0 + wm + mi * 16 + qr * 4 + i;
                if (MODE == 0) {
                    ((unsigned short*)Cv)[(size_t)gm * N + gn] = f2bf(acc[mi][ni][i]);
                } else {
                    const int t  = gm >> 3;
                    const int bb = gm & 7;
                    ((float*)Cv)[((size_t)bb * T_ + t) * NT + gn] =
                        acc[mi][ni][i] + bias[gn];
                }
            }
        }
    }
}

// ---------------------------------------------------------------------------
// Kernel 3b: 256x256-tile bf16 MFMA GEMM for the gate GEMMs.
// Fixed shape: M=4096, N=4096, K=1024, C bf16 gate-interleaved.
// 8 waves (2m x 4n, 128x64 out/wave), BK=32, TRIPLE-buffered LDS ring
// (3 x 32KB), counted vmcnt (steady state vmcnt(4), never drains), ONE raw
// s_barrier per K-tile, XOR-swizzled LDS (byte ^= ((byte>>7)&3)<<4 — a
// 16B-granular involution; read groups land 2x per bank-slot = free),
// s_setprio(1) around the 32-MFMA cluster.
// Hazard ledger (re-verified):
//  - vmcnt: prologue issues 8, waits vmcnt(4) -> tile 0 landed. Each body
//    issues 4, waits vmcnt(4) -> invariant "tile read next has landed".
//    Tail drains vmcnt(0) before the last tile's reads.
//  - buffer reuse distance is ONE barrier: body kt+1 stages tile kt+3 into
//    buf[kt%3], read in body kt. Safe: every wave's ds_reads of buf[kt%3]
//    are consumed by its MFMAs (compiler lgkmcnt waits) BEFORE it reaches
//    the barrier ending body kt, so all reads completed chip-wide before
//    any wave can issue the overwriting GLD16s after that barrier.
//  - GLD16 cannot cross the volatile vmcnt asm ("memory" clobber).
// ---------------------------------------------------------------------------
#define KT_BODY(CB, PB, KT2, DO_STAGE)                                        \
    {                                                                         \
        if (DO_STAGE) {                                                       \
            const size_t gk = (size_t)(KT2) * 64;                             \
            _Pragma("unroll") for (int s = 0; s < 2; ++s)                     \
                GLD16(Ab + (size_t)grow[s] * 2048 + gk + gcol[s],             \
                      (PB) + ((s * 8 + wid) << 10));                          \
            _Pragma("unroll") for (int s = 0; s < 2; ++s)                     \
                GLD16(Bb + (size_t)grow[s] * 2048 + gk + gcol[s],             \
                      (PB) + 16384 + ((s * 8 + wid) << 10));                  \
        }                                                                     \
        short8 af[8], bfv[4];                                                 \
        _Pragma("unroll") for (int mi = 0; mi < 8; ++mi)                      \
            af[mi] = *(const short8*)((CB) + aoff[mi]);                       \
        _Pragma("unroll") for (int ni = 0; ni < 4; ++ni)                      \
            bfv[ni] = *(const short8*)((CB) + boff[ni]);                      \
        __builtin_amdgcn_s_setprio(1);                                        \
        _Pragma("unroll") for (int mi = 0; mi < 8; ++mi)                      \
            _Pragma("unroll") for (int ni = 0; ni < 4; ++ni)                  \
                acc[mi][ni] = __builtin_amdgcn_mfma_f32_16x16x32_bf16(        \
                    af[mi], bfv[ni], acc[mi][ni], 0, 0, 0);                   \
        __builtin_amdgcn_s_setprio(0);                                        \
    }

__global__ __launch_bounds__(512, 2) void gemm256_gate(
    const unsigned short* __restrict__ A,   // [4096][1024] bf16
    const unsigned short* __restrict__ Bt,  // [4096][1024] bf16
    unsigned short* __restrict__ C) {       // [4096][4096] bf16
    __shared__ unsigned short lds[49152];   // 3 x (A 16KB + B 16KB) = 96 KB
    char* const sb = (char*)lds;

    const int tid  = threadIdx.x;
    const int lane = tid & 63;
    const int wid  = tid >> 6;              // 0..7
    const int wm   = wid >> 2;              // 0..1  (128-row half)
    const int wn   = wid & 3;               // 0..3  (64-col quarter)
    const int m0   = blockIdx.y * 256;
    const int n0   = blockIdx.x * 256;

    const char* Ab = (const char*)A  + (size_t)m0 * 2048;   // K=1024 -> 2048 B/row
    const char* Bb = (const char*)Bt + (size_t)n0 * 2048;

    // Staging source prep (pre-swizzled global address; LDS dest stays linear).
    // Tile-linear byte q -> source byte swz(q) = q ^ ((q>>7)&3)<<4 (involution).
    int grow[2], gcol[2];
    #pragma unroll
    for (int s = 0; s < 2; ++s) {
        const int q  = ((s * 8 + wid) << 10) + lane * 16;
        const int qs = q ^ (((q >> 7) & 3) << 4);
        grow[s] = qs >> 6;      // row within 256-row tile
        gcol[s] = qs & 63;      // byte within 64-B (=BK) row
    }
    // ds_read byte offsets (swizzled), loop-invariant per thread.
    const int rl = lane & 15;
    const int kb = (lane >> 4) * 16;        // 8-bf16 k-chunk
    int aoff[8], boff[4];
    #pragma unroll
    for (int mi = 0; mi < 8; ++mi) {
        const int q = (wm * 128 + mi * 16 + rl) * 64 + kb;
        aoff[mi] = q ^ (((q >> 7) & 3) << 4);
    }
    #pragma unroll
    for (int ni = 0; ni < 4; ++ni) {
        const int q = (wn * 64 + ni * 16 + rl) * 64 + kb;
        boff[ni] = 16384 + (q ^ (((q >> 7) & 3) << 4));
    }

    floatx4 acc[8][4];
    #pragma unroll
    for (int mi = 0; mi < 8; ++mi)
        #pragma unroll
        for (int ni = 0; ni < 4; ++ni)
            acc[mi][ni] = (floatx4){0.f, 0.f, 0.f, 0.f};

    char* const b0 = sb;
    char* const b1 = sb + 32768;
    char* const b2 = sb + 65536;

    // Prologue: stage K-tiles 0 -> b0 and 1 -> b1 (8 loads/thread).
    #pragma unroll
    for (int t = 0; t < 2; ++t) {
        char* pb = sb + t * 32768;
        const size_t gk = (size_t)t * 64;
        #pragma unroll
        for (int s = 0; s < 2; ++s)
            GLD16(Ab + (size_t)grow[s] * 2048 + gk + gcol[s],
                  pb + ((s * 8 + wid) << 10));
        #pragma unroll
        for (int s = 0; s < 2; ++s)
            GLD16(Bb + (size_t)grow[s] * 2048 + gk + gcol[s],
                  pb + 16384 + ((s * 8 + wid) << 10));
    }
    asm volatile("s_waitcnt vmcnt(4)" ::: "memory");   // K-tile 0 landed
    __builtin_amdgcn_s_barrier();

    // Main loop: 30 K-tiles (unrolled x3 so buffer ring is compile-time),
    // each body stages kt+2 and ends with vmcnt(4) + barrier.
    for (int kt = 0; kt < 30; kt += 3) {
        KT_BODY(b0, b2, kt + 2, true);
        asm volatile("s_waitcnt vmcnt(4)" ::: "memory");
        __builtin_amdgcn_s_barrier();
        KT_BODY(b1, b0, kt + 3, true);
        asm volatile("s_waitcnt vmcnt(4)" ::: "memory");
        __builtin_amdgcn_s_barrier();
        KT_BODY(b2, b1, kt + 4, true);
        asm volatile("s_waitcnt vmcnt(4)" ::: "memory");
        __builtin_amdgcn_s_barrier();
    }
    // Tail: kt = 30 (buf b0), kt = 31 (buf b1); no staging.
    KT_BODY(b0, b2, 0, false);
    asm volatile("s_waitcnt vmcnt(0)" ::: "memory");   // K-tile 31 landed
    __builtin_amdgcn_s_barrier();
    KT_BODY(b1, b0, 0, false);

    // Epilogue: C/D layout col=lane&15, row=(lane>>4)*4+i (verified m89/m91)
    const int cl = lane & 15;
    const int qr = lane >> 4;
    #pragma unroll
    for (int mi = 0; mi < 8; ++mi) {
        #pragma unroll
        for (int ni = 0; ni < 4; ++ni) {
            const int gn = n0 + wn * 64 + ni * 16 + cl;
            #pragma unroll
            for (int i = 0; i < 4; ++i) {
                const int gm = m0 + wm * 128 + mi * 16 + qr * 4 + i;
                C[(size_t)gm * NP + gn] = f2bf(acc[mi][ni][i]);
            }
        }
    }
}

// ---------------------------------------------------------------------------
// Kernel 4: SRU recurrence. One thread per (b,d). U4[t*8+b][d*4+{0..3}] packs
// {x_tilde, f_pre, r_pre, x} -> ONE uint2 load per t. 4-deep register
// pipeline; 16 vm-ops/stage so the steady-state wait is vmcnt(48) <= 63.
// ---------------------------------------------------------------------------
__global__ __launch_bounds__(64) void sru_scan(
    const unsigned short* __restrict__ U4,
    const float* __restrict__ v, const float* __restrict__ bvec,
    unsigned short* __restrict__ h) {
    const int idx = blockIdx.x * 64 + threadIdx.x;  // b*1024 + d
    const int d  = idx & (D_ - 1);

    const float vfn = -v[d];
    const float vrn = -v[D_ + d];
    const float bf_ = bvec[d];
    const float br_ = bvec[D_ + d];

    const uint2* up = (const uint2*)U4 + idx;   // per-t stride: 8192 uint2
    unsigned short* hp = h + idx;               // per-t stride: 8192 ushort

    constexpr int UNR  = 8;
    constexpr int PIPE = 4;
    constexpr int NB   = T_ / UNR;          // 64 stages
    constexpr size_t ST = (size_t)B_ * D_;  // 8192

    uint2 ub[PIPE][UNR];
    #pragma unroll
    for (int p = 0; p < PIPE; ++p)
        #pragma unroll
        for (int j = 0; j < UNR; ++j)
            ub[p][j] = up[(size_t)(p * UNR + j) * ST];

    float c = 0.0f;
    for (int bt = 0; bt < NB; bt += PIPE) {
        #pragma unroll
        for (int p = 0; p < PIPE; ++p) {
            const int s = bt + p;
            #pragma unroll
            for (int j = 0; j < UNR; ++j) {
                const uint2 u = ub[p][j];
                const float xt  = bf2f((unsigned short)(u.x & 0xFFFFu));
                const float fpp = bf2f((unsigned short)(u.x >> 16));
                const float rpp = bf2f((unsigned short)(u.y & 0xFFFFu));
                const float xi  = bf2f((unsigned short)(u.y >> 16));
                // chain: fma -> exp -> add -> rcp -> fma (~28 cyc/t)
                const float e1 = __expf(fmaf(vfn, c, -(fpp + bf_)));
                const float f  = __builtin_amdgcn_rcpf(1.0f + e1);
                c = fmaf(f, c - xt, xt);
                const float e2 = __expf(fmaf(vrn, c, -(rpp + br_)));
                const float r  = __builtin_amdgcn_rcpf(1.0f + e2);
                hp[(size_t)(s * UNR + j) * ST] = f2bf(fmaf(r, c - xi, xi));
            }
            if (s + PIPE < NB) {
                #pragma unroll
                for (int j = 0; j < UNR; ++j)
                    ub[p][j] = up[(size_t)((s + PIPE) * UNR + j) * ST];
            }
        }
    }
}

// ---------------------------------------------------------------------------
// Kernel 5: lengths // 2 as float
// ---------------------------------------------------------------------------
__global__ void lens_k(const int* __restrict__ lens, float* __restrict__ out) {
    const int i = threadIdx.x;
    if (i < B_) out[i] = (float)(lens[i] >> 1);
}

extern "C" void kernel_launch(void* const* d_in, const int* in_sizes, int n_in,
                              void* d_out, int out_size, void* d_ws, size_t ws_size,
                              hipStream_t stream) {
    const float* feats  = (const float*)d_in[0];
    const int*   lens   = (const int*)d_in[1];
    const float* conv_w = (const float*)d_in[2];
    const float* conv_b = (const float*)d_in[3];
    const float* sru_W  = (const float*)d_in[4];
    const float* sru_v  = (const float*)d_in[5];
    const float* sru_b  = (const float*)d_in[6];
    const float* fc_w   = (const float*)d_in[7];
    const float* fc_b   = (const float*)d_in[8];
    float* out = (float*)d_out;

    // ws: x0 8.4MB | x1 8.4MB | U4 33.5MB | Wt 4x8.4MB | WtF 1MB  (~85MB)
    unsigned short* x0 = (unsigned short*)d_ws;
    unsigned short* x1 = x0 + (size_t)M_ * D_;
    unsigned short* U4 = x1 + (size_t)M_ * D_;
    unsigned short* Wt = U4 + (size_t)M_ * NP;
    unsigned short* WtF = Wt + (size_t)L_ * NP * D_;

    // 1) conv + relu + transpose -> x0[t][b][f] bf16
    conv_relu_tr<<<dim3(T_ / 64, F_ / 32, B_), 256, 0, stream>>>(
        feats, conv_w, conv_b, x0);

    // 2) all weight transposes in one launch (j=3 rows = identity)
    prep_weights<<<dim3(32, 32, 17), 256, 0, stream>>>(sru_W, fc_w, Wt, WtF);

    // 3) SRU layers: 256^2-tile GEMM (N=4096 gate-interleaved bf16, x routed
    //    via identity block; grid 16x16 = exactly 1 block/CU) + scan
    unsigned short* cur = x0;
    unsigned short* nxt = x1;
    for (int l = 0; l < L_; ++l) {
        gemm256_gate<<<dim3(NP / 256, M_ / 256), 512, 0, stream>>>(
            cur, Wt + (size_t)l * NP * D_, U4);
        sru_scan<<<(B_ * D_) / 64, 64, 0, stream>>>(
            U4, sru_v + (size_t)l * 2 * D_, sru_b + (size_t)l * 2 * D_, nxt);
        unsigned short* tmp = cur; cur = nxt; nxt = tmp;
    }

    // 4) FC: logits[b][t][k] fp32 with bias + row remap (kept on 128^2 kernel)
    gemm_mfma<1><<<dim3(NT / 128, M_ / 128), 256, 0, stream>>>(
        cur, WtF, out, fc_b, NT, D_);

    // 5) lengths
    lens_k<<<1, 64, 0, stream>>>(lens, out + (size_t)M_ * NT);
}

// Round 3
// 709.720 us; speedup vs baseline: 1.1413x; 1.0194x over previous
//
#include <hip/hip_runtime.h>
#include <cstddef>
#include <cstdint>

// Problem constants
static constexpr int B_  = 8;
static constexpr int CIN = 16;
static constexpr int F_  = 1024;
static constexpr int T_  = 512;
static constexpr int D_  = 1024;
static constexpr int L_  = 4;
static constexpr int NT  = 512;         // N_TOKENS
static constexpr int M_  = T_ * B_;     // 4096 GEMM rows (m = t*8 + b)
static constexpr int K3  = 3 * D_;      // 3072
static constexpr int NP  = 4 * D_;      // 4096 = padded gate-interleaved N

typedef __attribute__((ext_vector_type(8))) short short8;   // 8 bf16 in 4 VGPRs
typedef __attribute__((ext_vector_type(4))) float floatx4;  // MFMA accumulator

__device__ __forceinline__ unsigned short f2bf(float f) {
    unsigned int u = __builtin_bit_cast(unsigned int, f);
    u += 0x7FFFu + ((u >> 16) & 1u);    // round-to-nearest-even
    return (unsigned short)(u >> 16);
}
__device__ __forceinline__ float bf2f(unsigned short s) {
    unsigned int u = ((unsigned int)s) << 16;
    return __builtin_bit_cast(float, u);
}

// async 16B/lane global->LDS (lds base wave-uniform; HW scatters lane*16)
#define GLD16(g, l)                                                              \
    __builtin_amdgcn_global_load_lds(                                            \
        (__attribute__((address_space(1))) unsigned int*)(g),                    \
        (__attribute__((address_space(3))) unsigned int*)(l), 16, 0, 0)

// ---------------------------------------------------------------------------
// Kernel 1: x_bf16[t][b][f] = relu( sum_c feats[b][c][f][t]*w[c] + bias )
// 32(f) x 64(t) tile, float4 reads along t, LDS transpose, ushort4 writes.
// ---------------------------------------------------------------------------
__global__ __launch_bounds__(256) void conv_relu_tr(
    const float* __restrict__ feats, const float* __restrict__ wv,
    const float* __restrict__ bv, unsigned short* __restrict__ x0) {
    __shared__ float tile[32][68];      // [f][t], padded for float4 rows
    const int b  = blockIdx.z;
    const int f0 = blockIdx.y * 32;
    const int t0 = blockIdx.x * 64;
    const float bias = bv[0];

    const int t4 = threadIdx.x & 15;    // t-offset/4
    const int fi = threadIdx.x >> 4;    // 0..15
    #pragma unroll
    for (int fo = 0; fo < 32; fo += 16) {
        const int f = fo + fi;
        float4 acc = {bias, bias, bias, bias};
        const float* p = feats + (((size_t)b * CIN) * F_ + (f0 + f)) * T_ + t0 + t4 * 4;
        #pragma unroll
        for (int c = 0; c < CIN; ++c) {
            const float4 vv = *(const float4*)(p + (size_t)c * F_ * T_);
            const float w = wv[c];
            acc.x += w * vv.x; acc.y += w * vv.y;
            acc.z += w * vv.z; acc.w += w * vv.w;
        }
        acc.x = fmaxf(acc.x, 0.f); acc.y = fmaxf(acc.y, 0.f);
        acc.z = fmaxf(acc.z, 0.f); acc.w = fmaxf(acc.w, 0.f);
        *(float4*)&tile[f][t4 * 4] = acc;
    }
    __syncthreads();
    const int f4 = threadIdx.x & 7;     // f-offset/4
    const int tr = threadIdx.x >> 3;    // 0..31
    #pragma unroll
    for (int to = 0; to < 64; to += 32) {
        const int t = to + tr;
        unsigned short pk[4];
        #pragma unroll
        for (int q = 0; q < 4; ++q) pk[q] = f2bf(tile[f4 * 4 + q][t]);
        *(uint2*)&x0[(size_t)(t0 + t) * (B_ * D_) + (size_t)b * D_ + f0 + f4 * 4] =
            *(const uint2*)pk;
    }
}

// ---------------------------------------------------------------------------
// Kernel 2: weight prep (one launch, grid z = 0..16):
//  z<16: l=z>>2, j=z&3:  Wt[l][d*4+j][k] = bf16(sru_W[l][k][j*1024+d])
//        j==3 -> IDENTITY row e_d (routes x through the GEMM exactly)
//  z==16 (blockIdx.x<16): WtF[n][k] = bf16(fc_w[k][n])
// ---------------------------------------------------------------------------
__global__ __launch_bounds__(256) void prep_weights(
    const float* __restrict__ sru_W, const float* __restrict__ fc_w,
    unsigned short* __restrict__ Wt, unsigned short* __restrict__ WtF) {
    __shared__ float tile[32][33];
    const int z  = blockIdx.z;
    const int x  = threadIdx.x & 31;
    const int y8 = threadIdx.x >> 5;    // 0..7
    if (z < 16) {
        const int l = z >> 2, j = z & 3;
        const int d0 = blockIdx.x * 32;
        const int k0 = blockIdx.y * 32;
        unsigned short* Wo = Wt + (size_t)l * ((size_t)NP * D_);
        if (j < 3) {
            const float* W = sru_W + (size_t)l * D_ * K3;
            #pragma unroll
            for (int yo = 0; yo < 32; yo += 8)
                tile[yo + y8][x] = W[(size_t)(k0 + yo + y8) * K3 + j * D_ + d0 + x];
            __syncthreads();
            #pragma unroll
            for (int yo = 0; yo < 32; yo += 8) {
                const int dy = yo + y8;
                Wo[(size_t)((d0 + dy) * 4 + j) * D_ + k0 + x] = f2bf(tile[x][dy]);
            }
        } else {
            #pragma unroll
            for (int yo = 0; yo < 32; yo += 8) {
                const int dy = d0 + yo + y8;
                Wo[(size_t)(dy * 4 + 3) * D_ + k0 + x] =
                    (k0 + x == dy) ? (unsigned short)0x3F80u : (unsigned short)0u;
            }
        }
    } else {
        if (blockIdx.x >= NT / 32) return;
        const int n0 = blockIdx.x * 32;
        const int k0 = blockIdx.y * 32;
        #pragma unroll
        for (int yo = 0; yo < 32; yo += 8)
            tile[yo + y8][x] = fc_w[(size_t)(k0 + yo + y8) * NT + n0 + x];
        __syncthreads();
        #pragma unroll
        for (int yo = 0; yo < 32; yo += 8)
            WtF[(size_t)(n0 + yo + y8) * D_ + k0 + x] = f2bf(tile[x][yo + y8]);
    }
}

// ---------------------------------------------------------------------------
// Kernel 3: bf16 MFMA GEMM  C[M][N] = A[M][K] * Bt[N][K]^T  (m97 structure)
// FC only: fp32 out, +bias, row remap; also writes lens output (block 0).
// ---------------------------------------------------------------------------
__global__ __launch_bounds__(256) void gemm_fc(
    const unsigned short* __restrict__ A,   // [M][K] bf16
    const unsigned short* __restrict__ Bt,  // [N][K] bf16
    float* __restrict__ Cv, const float* __restrict__ bias,
    const int* __restrict__ lens, float* __restrict__ lout,
    int N, int K) {
    __shared__ unsigned short As[128 * 32];
    __shared__ unsigned short Bs[128 * 32];

    const int tid  = threadIdx.x;
    const int lane = tid & 63;
    const int wid  = tid >> 6;
    const int m0 = blockIdx.y * 128;
    const int n0 = blockIdx.x * 128;
    const int wm = (wid >> 1) * 64;
    const int wn = (wid & 1) * 64;

    // folded lens kernel: lens//2 as float (block (0,0) only; no deps)
    if (blockIdx.x == 0 && blockIdx.y == 0 && tid < B_)
        lout[tid] = (float)(lens[tid] >> 1);

    floatx4 acc[4][4];
    #pragma unroll
    for (int mi = 0; mi < 4; ++mi)
        #pragma unroll
        for (int ni = 0; ni < 4; ++ni)
            acc[mi][ni] = (floatx4){0.f, 0.f, 0.f, 0.f};

    const char* gA = (const char*)A;
    const char* gB = (const char*)Bt;
    const size_t rowstride = (size_t)K * 2;
    const size_t rA0 = (size_t)(m0 + (tid >> 2)) * rowstride + (tid & 3) * 16;
    const size_t rB0 = (size_t)(n0 + (tid >> 2)) * rowstride + (tid & 3) * 16;
    const size_t pstep = 64 * rowstride;
    char* sA = (char*)As;
    char* sB = (char*)Bs;
    const int ldsbase = wid * 1024;

    const int rsel = lane & 15;
    const int koff = (lane >> 4) * 16;   // byte offset of 8-bf16 k-group

    for (int k0 = 0; k0 < K; k0 += 32) {
        const size_t kb = (size_t)k0 * 2;
        GLD16(gA + rA0 + kb,         sA + ldsbase);
        GLD16(gA + rA0 + kb + pstep, sA + ldsbase + 4096);
        GLD16(gB + rB0 + kb,         sB + ldsbase);
        GLD16(gB + rB0 + kb + pstep, sB + ldsbase + 4096);
        __syncthreads();

        short8 af[4], bfv[4];
        #pragma unroll
        for (int mi = 0; mi < 4; ++mi)
            af[mi] = *(const short8*)(sA + ((wm + mi * 16 + rsel) * 64 + koff));
        #pragma unroll
        for (int ni = 0; ni < 4; ++ni)
            bfv[ni] = *(const short8*)(sB + ((wn + ni * 16 + rsel) * 64 + koff));
        #pragma unroll
        for (int mi = 0; mi < 4; ++mi)
            #pragma unroll
            for (int ni = 0; ni < 4; ++ni)
                acc[mi][ni] = __builtin_amdgcn_mfma_f32_16x16x32_bf16(
                    af[mi], bfv[ni], acc[mi][ni], 0, 0, 0);
        __syncthreads();
    }

    // C/D layout: col=lane&15, row=(lane>>4)*4+i  (verified m89/m91)
    const int cl = lane & 15;
    const int qr = lane >> 4;
    #pragma unroll
    for (int mi = 0; mi < 4; ++mi) {
        #pragma unroll
        for (int ni = 0; ni < 4; ++ni) {
            const int gn = n0 + wn + ni * 16 + cl;
            #pragma unroll
            for (int i = 0; i < 4; ++i) {
                const int gm = m0 + wm + mi * 16 + qr * 4 + i;
                const int t  = gm >> 3;
                const int bb = gm & 7;
                Cv[((size_t)bb * T_ + t) * NT + gn] = acc[mi][ni][i] + bias[gn];
            }
        }
    }
}

// ---------------------------------------------------------------------------
// Kernel 3b: 256x256-tile bf16 MFMA GEMM for the gate GEMMs.
// Fixed shape: M=4096, N=4096, K=1024, C bf16 gate-interleaved.
// 8 waves (2m x 4n, 128x64 out/wave), BK=32, TRIPLE-buffered LDS ring
// (3 x 32KB), counted vmcnt (steady state vmcnt(4), never drains),
// XOR-swizzled LDS (byte ^= ((byte>>7)&3)<<4, both-sides involution),
// s_setprio(1) around MFMA clusters.
// NEW: each K-tile body is split into TWO phases, each {stage-issue ||
// ds_read || 16 MFMA}, separated by one extra barrier -> wave role
// diversity (T3/T5 mechanism, m248v2 +10%) while keeping the verified
// ledger: stage split 2+2 across phases, so outstanding at the end-of-tile
// vmcnt(4) is still exactly tile kt+2's 4 loads.
// Hazard ledger (unchanged):
//  - vmcnt: prologue issues 8, waits vmcnt(4) -> tile 0 landed. Each body
//    issues 2+2, waits vmcnt(4) at end -> tile kt+1 fully landed before
//    body kt+1 reads it. Tail drains vmcnt(0) before the last tile.
//  - buffer reuse distance >= ONE barrier: all ds_reads of buf[kt%3] are
//    consumed by MFMAs (compiler lgkmcnt) before the barrier ending body
//    kt; the overwriting GLD16s for tile kt+3 issue after that barrier.
//    The mid-tile barrier only tightens this.
//  - GLD16 cannot cross the volatile vmcnt asm ("memory" clobber).
// ---------------------------------------------------------------------------
#define KT_BODY(CB, PB, KT2, DO_STAGE)                                        \
    {                                                                         \
        if (DO_STAGE) { /* phase A: stage the two A-halves of tile KT2 */     \
            const size_t gk = (size_t)(KT2) * 64;                             \
            _Pragma("unroll") for (int s = 0; s < 2; ++s)                     \
                GLD16(Ab + (size_t)grow[s] * 2048 + gk + gcol[s],             \
                      (PB) + ((s * 8 + wid) << 10));                          \
        }                                                                     \
        short8 af[8], bf01[2], bf23[2];                                       \
        _Pragma("unroll") for (int mi = 0; mi < 8; ++mi)                      \
            af[mi] = *(const short8*)((CB) + aoff[mi]);                       \
        _Pragma("unroll") for (int ni = 0; ni < 2; ++ni)                      \
            bf01[ni] = *(const short8*)((CB) + boff[ni]);                     \
        __builtin_amdgcn_s_setprio(1);                                        \
        _Pragma("unroll") for (int mi = 0; mi < 8; ++mi)                      \
            _Pragma("unroll") for (int ni = 0; ni < 2; ++ni)                  \
                acc[mi][ni] = __builtin_amdgcn_mfma_f32_16x16x32_bf16(        \
                    af[mi], bf01[ni], acc[mi][ni], 0, 0, 0);                  \
        __builtin_amdgcn_s_setprio(0);                                        \
        __builtin_amdgcn_s_barrier();                                         \
        if (DO_STAGE) { /* phase B: stage the two B-halves of tile KT2 */     \
            const size_t gk = (size_t)(KT2) * 64;                             \
            _Pragma("unroll") for (int s = 0; s < 2; ++s)                     \
                GLD16(Bb + (size_t)grow[s] * 2048 + gk + gcol[s],             \
                      (PB) + 16384 + ((s * 8 + wid) << 10));                  \
        }                                                                     \
        _Pragma("unroll") for (int ni = 0; ni < 2; ++ni)                      \
            bf23[ni] = *(const short8*)((CB) + boff[2 + ni]);                 \
        __builtin_amdgcn_s_setprio(1);                                        \
        _Pragma("unroll") for (int mi = 0; mi < 8; ++mi)                      \
            _Pragma("unroll") for (int ni = 0; ni < 2; ++ni)                  \
                acc[mi][2 + ni] = __builtin_amdgcn_mfma_f32_16x16x32_bf16(    \
                    af[mi], bf23[ni], acc[mi][2 + ni], 0, 0, 0);              \
        __builtin_amdgcn_s_setprio(0);                                        \
    }

__global__ __launch_bounds__(512, 2) void gemm256_gate(
    const unsigned short* __restrict__ A,   // [4096][1024] bf16
    const unsigned short* __restrict__ Bt,  // [4096][1024] bf16
    unsigned short* __restrict__ C) {       // [4096][4096] bf16
    __shared__ unsigned short lds[49152];   // 3 x (A 16KB + B 16KB) = 96 KB
    char* const sb = (char*)lds;

    const int tid  = threadIdx.x;
    const int lane = tid & 63;
    const int wid  = tid >> 6;              // 0..7
    const int wm   = wid >> 2;              // 0..1  (128-row half)
    const int wn   = wid & 3;               // 0..3  (64-col quarter)
    const int m0   = blockIdx.y * 256;
    const int n0   = blockIdx.x * 256;

    const char* Ab = (const char*)A  + (size_t)m0 * 2048;   // K=1024 -> 2048 B/row
    const char* Bb = (const char*)Bt + (size_t)n0 * 2048;

    // Staging source prep (pre-swizzled global address; LDS dest stays linear).
    // Tile-linear byte q -> source byte swz(q) = q ^ ((q>>7)&3)<<4 (involution).
    int grow[2], gcol[2];
    #pragma unroll
    for (int s = 0; s < 2; ++s) {
        const int q  = ((s * 8 + wid) << 10) + lane * 16;
        const int qs = q ^ (((q >> 7) & 3) << 4);
        grow[s] = qs >> 6;      // row within 256-row tile
        gcol[s] = qs & 63;      // byte within 64-B (=BK) row
    }
    // ds_read byte offsets (swizzled), loop-invariant per thread.
    const int rl = lane & 15;
    const int kb = (lane >> 4) * 16;        // 8-bf16 k-chunk
    int aoff[8], boff[4];
    #pragma unroll
    for (int mi = 0; mi < 8; ++mi) {
        const int q = (wm * 128 + mi * 16 + rl) * 64 + kb;
        aoff[mi] = q ^ (((q >> 7) & 3) << 4);
    }
    #pragma unroll
    for (int ni = 0; ni < 4; ++ni) {
        const int q = (wn * 64 + ni * 16 + rl) * 64 + kb;
        boff[ni] = 16384 + (q ^ (((q >> 7) & 3) << 4));
    }

    floatx4 acc[8][4];
    #pragma unroll
    for (int mi = 0; mi < 8; ++mi)
        #pragma unroll
        for (int ni = 0; ni < 4; ++ni)
            acc[mi][ni] = (floatx4){0.f, 0.f, 0.f, 0.f};

    char* const b0 = sb;
    char* const b1 = sb + 32768;
    char* const b2 = sb + 65536;

    // Prologue: stage K-tiles 0 -> b0 and 1 -> b1 (8 loads/thread).
    #pragma unroll
    for (int t = 0; t < 2; ++t) {
        char* pb = sb + t * 32768;
        const size_t gk = (size_t)t * 64;
        #pragma unroll
        for (int s = 0; s < 2; ++s)
            GLD16(Ab + (size_t)grow[s] * 2048 + gk + gcol[s],
                  pb + ((s * 8 + wid) << 10));
        #pragma unroll
        for (int s = 0; s < 2; ++s)
            GLD16(Bb + (size_t)grow[s] * 2048 + gk + gcol[s],
                  pb + 16384 + ((s * 8 + wid) << 10));
    }
    asm volatile("s_waitcnt vmcnt(4)" ::: "memory");   // K-tile 0 landed
    __builtin_amdgcn_s_barrier();

    // Main loop: 30 K-tiles (unrolled x3 so buffer ring is compile-time),
    // each body stages kt+2 (2+2 across its phases), ends vmcnt(4)+barrier.
    for (int kt = 0; kt < 30; kt += 3) {
        KT_BODY(b0, b2, kt + 2, true);
        asm volatile("s_waitcnt vmcnt(4)" ::: "memory");
        __builtin_amdgcn_s_barrier();
        KT_BODY(b1, b0, kt + 3, true);
        asm volatile("s_waitcnt vmcnt(4)" ::: "memory");
        __builtin_amdgcn_s_barrier();
        KT_BODY(b2, b1, kt + 4, true);
        asm volatile("s_waitcnt vmcnt(4)" ::: "memory");
        __builtin_amdgcn_s_barrier();
    }
    // Tail: kt = 30 (buf b0), kt = 31 (buf b1); no staging.
    KT_BODY(b0, b2, 0, false);
    asm volatile("s_waitcnt vmcnt(0)" ::: "memory");   // K-tile 31 landed
    __builtin_amdgcn_s_barrier();
    KT_BODY(b1, b0, 0, false);

    // Epilogue: C/D layout col=lane&15, row=(lane>>4)*4+i (verified m89/m91)
    const int cl = lane & 15;
    const int qr = lane >> 4;
    #pragma unroll
    for (int mi = 0; mi < 8; ++mi) {
        #pragma unroll
        for (int ni = 0; ni < 4; ++ni) {
            const int gn = n0 + wn * 64 + ni * 16 + cl;
            #pragma unroll
            for (int i = 0; i < 4; ++i) {
                const int gm = m0 + wm * 128 + mi * 16 + qr * 4 + i;
                C[(size_t)gm * NP + gn] = f2bf(acc[mi][ni][i]);
            }
        }
    }
}

// ---------------------------------------------------------------------------
// Kernel 4: SRU recurrence. One thread per (b,d). U4[t*8+b][d*4+{0..3}] packs
// {x_tilde, f_pre, r_pre, x} -> ONE uint2 load per t. 4-deep register
// pipeline; 16 vm-ops/stage so the steady-state wait is vmcnt(48) <= 63.
// Sigmoid in exp2 form: the x(log2 e) scaling is folded into loop-invariant
// constants (vf2, mbfL) and a per-t fma OFF the serial c-chain; the chain is
// fma -> v_exp -> add -> rcp -> fma (~28 cyc/t, was ~32 with __expf's mul).
// ---------------------------------------------------------------------------
__global__ __launch_bounds__(64) void sru_scan(
    const unsigned short* __restrict__ U4,
    const float* __restrict__ v, const float* __restrict__ bvec,
    unsigned short* __restrict__ h) {
    const int idx = blockIdx.x * 64 + threadIdx.x;  // b*1024 + d
    const int d  = idx & (D_ - 1);

    constexpr float L2E = 1.44269504088896340736f;
    const float vf2  = -v[d] * L2E;          // -vf * log2e
    const float vr2  = -v[D_ + d] * L2E;     // -vr * log2e
    const float mbfL = -bvec[d] * L2E;       // -bf * log2e
    const float mbrL = -bvec[D_ + d] * L2E;  // -br * log2e

    const uint2* up = (const uint2*)U4 + idx;   // per-t stride: 8192 uint2
    unsigned short* hp = h + idx;               // per-t stride: 8192 ushort

    constexpr int UNR  = 8;
    constexpr int PIPE = 4;
    constexpr int NB   = T_ / UNR;          // 64 stages
    constexpr size_t ST = (size_t)B_ * D_;  // 8192

    uint2 ub[PIPE][UNR];
    #pragma unroll
    for (int p = 0; p < PIPE; ++p)
        #pragma unroll
        for (int j = 0; j < UNR; ++j)
            ub[p][j] = up[(size_t)(p * UNR + j) * ST];

    float c = 0.0f;
    for (int bt = 0; bt < NB; bt += PIPE) {
        #pragma unroll
        for (int p = 0; p < PIPE; ++p) {
            const int s = bt + p;
            #pragma unroll
            for (int j = 0; j < UNR; ++j) {
                const uint2 u = ub[p][j];
                const float xt  = bf2f((unsigned short)(u.x & 0xFFFFu));
                const float fpp = bf2f((unsigned short)(u.x >> 16));
                const float rpp = bf2f((unsigned short)(u.y & 0xFFFFu));
                const float xi  = bf2f((unsigned short)(u.y >> 16));
                const float pre1 = fmaf(fpp, -L2E, mbfL);   // off c-chain
                const float pre2 = fmaf(rpp, -L2E, mbrL);   // off c-chain
                float e1;
                asm("v_exp_f32 %0, %1" : "=v"(e1) : "v"(fmaf(vf2, c, pre1)));
                const float f  = __builtin_amdgcn_rcpf(1.0f + e1);
                c = fmaf(f, c - xt, xt);
                float e2;
                asm("v_exp_f32 %0, %1" : "=v"(e2) : "v"(fmaf(vr2, c, pre2)));
                const float r  = __builtin_amdgcn_rcpf(1.0f + e2);
                hp[(size_t)(s * UNR + j) * ST] = f2bf(fmaf(r, c - xi, xi));
            }
            if (s + PIPE < NB) {
                #pragma unroll
                for (int j = 0; j < UNR; ++j)
                    ub[p][j] = up[(size_t)((s + PIPE) * UNR + j) * ST];
            }
        }
    }
}

extern "C" void kernel_launch(void* const* d_in, const int* in_sizes, int n_in,
                              void* d_out, int out_size, void* d_ws, size_t ws_size,
                              hipStream_t stream) {
    const float* feats  = (const float*)d_in[0];
    const int*   lens   = (const int*)d_in[1];
    const float* conv_w = (const float*)d_in[2];
    const float* conv_b = (const float*)d_in[3];
    const float* sru_W  = (const float*)d_in[4];
    const float* sru_v  = (const float*)d_in[5];
    const float* sru_b  = (const float*)d_in[6];
    const float* fc_w   = (const float*)d_in[7];
    const float* fc_b   = (const float*)d_in[8];
    float* out = (float*)d_out;

    // ws: x0 8.4MB | x1 8.4MB | U4 33.5MB | Wt 4x8.4MB | WtF 1MB  (~85MB)
    unsigned short* x0 = (unsigned short*)d_ws;
    unsigned short* x1 = x0 + (size_t)M_ * D_;
    unsigned short* U4 = x1 + (size_t)M_ * D_;
    unsigned short* Wt = U4 + (size_t)M_ * NP;
    unsigned short* WtF = Wt + (size_t)L_ * NP * D_;

    // 1) conv + relu + transpose -> x0[t][b][f] bf16
    conv_relu_tr<<<dim3(T_ / 64, F_ / 32, B_), 256, 0, stream>>>(
        feats, conv_w, conv_b, x0);

    // 2) all weight transposes in one launch (j=3 rows = identity)
    prep_weights<<<dim3(32, 32, 17), 256, 0, stream>>>(sru_W, fc_w, Wt, WtF);

    // 3) SRU layers: 256^2-tile GEMM (N=4096 gate-interleaved bf16, x routed
    //    via identity block; grid 16x16 = exactly 1 block/CU) + scan
    unsigned short* cur = x0;
    unsigned short* nxt = x1;
    for (int l = 0; l < L_; ++l) {
        gemm256_gate<<<dim3(NP / 256, M_ / 256), 512, 0, stream>>>(
            cur, Wt + (size_t)l * NP * D_, U4);
        sru_scan<<<(B_ * D_) / 64, 64, 0, stream>>>(
            U4, sru_v + (size_t)l * 2 * D_, sru_b + (size_t)l * 2 * D_, nxt);
        unsigned short* tmp = cur; cur = nxt; nxt = tmp;
    }

    // 4) FC: logits[b][t][k] fp32 with bias + row remap; lens folded in
    gemm_fc<<<dim3(NT / 128, M_ / 128), 256, 0, stream>>>(
        cur, WtF, out, fc_b, lens, out + (size_t)M_ * NT, NT, D_);
}